// Round 9
// baseline (199.816 us; speedup 1.0000x reference)
//
#include <hip/hip_runtime.h>
#include <stdint.h>

#define B_ 2
#define S_ 2048
#define D_ 1024
#define H_ 16
#define HD_ 64
#define M_ (B_*S_)   // 4096

typedef __bf16 bf16;
typedef __attribute__((ext_vector_type(8))) __bf16 bf16x8;
typedef __attribute__((ext_vector_type(4))) float f32x4;
typedef __attribute__((ext_vector_type(2))) float f32x2;

// async global->LDS, 16B per lane. LDS dest = uniform base + lane*16.
__device__ __forceinline__ void gload16(const bf16* g, bf16* l) {
    __builtin_amdgcn_global_load_lds(
        (const __attribute__((address_space(1))) void*)g,
        (__attribute__((address_space(3))) void*)l, 16, 0, 0);
}

// ---------------- fp32 -> bf16 converts (single launch) ----------------
__global__ void k_cvt_all(const float* __restrict__ hs,
                          const float* __restrict__ Wq, const float* __restrict__ Wk,
                          const float* __restrict__ Wv, const float* __restrict__ Wo,
                          bf16* __restrict__ hb,
                          bf16* __restrict__ wqb, bf16* __restrict__ wkb,
                          bf16* __restrict__ wvb, bf16* __restrict__ wob) {
    int blk = blockIdx.x;
    const float* s; bf16* d; int base;
    if (blk < 2048) { s = hs; d = hb; base = blk; }
    else {
        int r = blk - 2048; int which = r >> 9; base = r & 511;
        s = (which==0)?Wq:(which==1)?Wk:(which==2)?Wv:Wo;
        d = (which==0)?wqb:(which==1)?wkb:(which==2)?wvb:wob;
    }
    int idx = base*2048 + threadIdx.x*8;
    float4 a = *(const float4*)(s + idx);
    float4 b = *(const float4*)(s + idx + 4);
    bf16 o[8] = {(bf16)a.x,(bf16)a.y,(bf16)a.z,(bf16)a.w,
                 (bf16)b.x,(bf16)b.y,(bf16)b.z,(bf16)b.w};
    *(int4*)(d + idx) = *(const int4*)o;
}

// ---------------- fused QKV projection GEMM (z-fused, BK=128) ----------------
// One block computes Q, K and V for its (m-panel, head) pair. A[128 x 128k]
// staged once serves 3 weight tiles [64n x 128k]. BK=128 pair-K processing:
// 8 iterations x {stage 20 DMAs, barrier, 96 MFMA/wave, barrier} -> 16
// barriers instead of 32 (r8 proved GEMM staging is NOT latency-bound; the
// cost is barrier frequency, per attn v8's -4.7us from barrier halving).
// Layouts: As[2 half][128][64] 32KB, Bsf[3 z][2 half][64][64] 48KB = 80KB.
__global__ __launch_bounds__(256) void k_gemm_qkv(
    const bf16* __restrict__ X,
    const bf16* __restrict__ Wq, const bf16* __restrict__ Wk, const bf16* __restrict__ Wv,
    const float* __restrict__ bq, const float* __restrict__ bk, const float* __restrict__ bv,
    bf16* __restrict__ Qo, bf16* __restrict__ Ko, bf16* __restrict__ Vo)
{
    const int hh = blockIdx.x;           // head = n-tile (64-aligned)
    const int n0 = hh * 64;
    const int m0 = blockIdx.y * 128;
    const int t = threadIdx.x;
    const int w = t >> 6, lane = t & 63, quad = lane >> 4, l15 = lane & 15;
    const int lr = lane >> 3;
    const int lc = (lane & 7) ^ lr;
    const int sx = l15 & 7;
    const int mw = (w >> 1) * 64, nw = (w & 1) * 32;

    __shared__ __align__(16) char smraw[81920];  // As 32K | Bsf 48K; epi aliases
    bf16* As  = (bf16*)smraw;               // [2][128][64]
    bf16* Bsf = (bf16*)(smraw + 32768);     // [3][2][64][64]
    bf16* epi = (bf16*)smraw;               // [128][72] or [64][136]

    f32x4 acc[3][4][2];
    #pragma unroll
    for (int z = 0; z < 3; z++)
        #pragma unroll
        for (int i = 0; i < 4; i++)
            #pragma unroll
            for (int j = 0; j < 2; j++)
                acc[z][i][j] = (f32x4){0.f,0.f,0.f,0.f};

    const bf16* gA = X + (size_t)(m0 + w*8 + lr)*D_ + lc*8;
    const bf16* Wz[3] = {Wq, Wk, Wv};
    const bf16* gB[6];
    #pragma unroll
    for (int cc = 0; cc < 6; cc++) {
        const int z = cc >> 1;
        const int rowz = (cc & 1)*32 + w*8 + lr;
        gB[cc] = Wz[z] + (size_t)(n0 + rowz)*D_ + lc*8;
    }

    for (int k0 = 0; k0 < D_; k0 += 128) {
        // stage both 64-wide halves of the K-pair
        #pragma unroll
        for (int h = 0; h < 2; h++) {
            #pragma unroll
            for (int c = 0; c < 4; c++)
                gload16(gA + (size_t)c*32*D_ + k0 + h*64, &As[h*8192 + c*2048 + w*512]);
            #pragma unroll
            for (int cc = 0; cc < 6; cc++)
                gload16(gB[cc] + k0 + h*64,
                        &Bsf[(cc>>1)*8192 + h*4096 + (cc&1)*2048 + w*512]);
        }
        __syncthreads();
        #pragma unroll
        for (int h = 0; h < 2; h++) {
            #pragma unroll
            for (int ks = 0; ks < 2; ks++) {
                bf16x8 af[4], bfr[3][2];
                #pragma unroll
                for (int i = 0; i < 4; i++)
                    af[i] = *(const bf16x8*)&As[h*8192 + (mw + i*16 + l15)*64 + (((ks*4+quad)^sx)*8)];
                #pragma unroll
                for (int z = 0; z < 3; z++)
                    #pragma unroll
                    for (int j = 0; j < 2; j++)
                        bfr[z][j] = *(const bf16x8*)&Bsf[z*8192 + h*4096 + (nw + j*16 + l15)*64 + (((ks*4+quad)^sx)*8)];
                __builtin_amdgcn_s_setprio(1);
                #pragma unroll
                for (int z = 0; z < 3; z++)
                    #pragma unroll
                    for (int i = 0; i < 4; i++)
                        #pragma unroll
                        for (int j = 0; j < 2; j++)
                            acc[z][i][j] = __builtin_amdgcn_mfma_f32_16x16x32_bf16(af[i], bfr[z][j], acc[z][i][j], 0, 0, 0);
                __builtin_amdgcn_s_setprio(0);
            }
        }
        __syncthreads();
    }

    // ---- epilogues (per z, sequential through the aliased epi buffer) ----
    // z = 0 (Q, scale 1/8) and z = 1 (K): epi[m=128][stride 72], row-coalesced store
    #pragma unroll
    for (int z = 0; z < 2; z++) {
        const float scale = z ? 1.0f : 0.125f;
        const float* bias = z ? bk : bq;
        bf16* Out = z ? Ko : Qo;
        #pragma unroll
        for (int j = 0; j < 2; j++) {
            int n = nw + j*16 + l15;
            float bn = bias[n0 + n];
            #pragma unroll
            for (int i = 0; i < 4; i++) {
                int mloc = mw + i*16 + quad*4;
                #pragma unroll
                for (int r = 0; r < 4; r++)
                    epi[(mloc + r)*72 + n] = (bf16)((acc[z][i][j][r] + bn) * scale);
            }
        }
        __syncthreads();
        #pragma unroll
        for (int p = 0; p < 4; p++) {
            int c = t + 256*p;
            int row = c >> 3;             // local m
            int ncol = (c & 7) * 8;       // local n (hd)
            int4 val = *(const int4*)&epi[row*72 + ncol];
            int m = m0 + row; int bb = m >> 11, s = m & 2047;
            *(int4*)&Out[((size_t)((bb*H_ + hh)*S_ + s))*HD_ + ncol] = val;
        }
        __syncthreads();
    }
    // z = 2 (V): epi[n=64][m stride 136], m-coalesced (transposed) store
    {
        #pragma unroll
        for (int j = 0; j < 2; j++) {
            int n = nw + j*16 + l15;
            float bn = bv[n0 + n];
            #pragma unroll
            for (int i = 0; i < 4; i++) {
                int mloc = mw + i*16 + quad*4;
                union { bf16 h4[4]; uint2 u; } pk;
                #pragma unroll
                for (int r = 0; r < 4; r++) pk.h4[r] = (bf16)(acc[2][i][j][r] + bn);
                *(uint2*)&epi[n*136 + mloc] = pk.u;
            }
        }
        __syncthreads();
        #pragma unroll
        for (int p = 0; p < 4; p++) {
            int c = t + 256*p;
            int row = c >> 4;             // local n (hd)
            int mcol = (c & 15) * 8;      // local m (token)
            int4 val = *(const int4*)&epi[row*136 + mcol];
            int m = m0 + mcol; int bb = m >> 11, s = m & 2047;
            *(int4*)&Vo[((size_t)((bb*H_ + hh)*HD_ + row))*S_ + s] = val;
        }
    }
}

// ---------------- output projection GEMM (64x128 tile, BK=128) ----------------
// Same pair-K transform: As[2][64][64] 16KB + Bs[2][128][64] 32KB = 48KB,
// 8 iterations, 16 barriers instead of 32.
__global__ __launch_bounds__(256) void k_gemm_out(
    const bf16* __restrict__ X, const bf16* __restrict__ W,
    const float* __restrict__ bias, float* __restrict__ Out)
{
    const int n0 = blockIdx.x * 128;
    const int m0 = blockIdx.y * 64;
    const int t = threadIdx.x;
    const int w = t >> 6, lane = t & 63, quad = lane >> 4, l15 = lane & 15;
    const int lr = lane >> 3;
    const int lc = (lane & 7) ^ lr;
    const int sx = l15 & 7;
    const int nw = w * 32;

    __shared__ __align__(16) bf16 As[2*64*64];    // 16 KB
    __shared__ __align__(16) bf16 Bs[2*128*64];   // 32 KB

    f32x4 acc[4][2];
    #pragma unroll
    for (int i = 0; i < 4; i++)
        #pragma unroll
        for (int j = 0; j < 2; j++)
            acc[i][j] = (f32x4){0.f,0.f,0.f,0.f};

    const bf16* gA = X + (size_t)(m0 + w*8 + lr)*D_ + lc*8;
    const bf16* gB = W + (size_t)(n0 + w*8 + lr)*D_ + lc*8;

    for (int k0 = 0; k0 < D_; k0 += 128) {
        #pragma unroll
        for (int h = 0; h < 2; h++) {
            #pragma unroll
            for (int c = 0; c < 2; c++)
                gload16(gA + (size_t)c*32*D_ + k0 + h*64, &As[h*4096 + c*2048 + w*512]);
            #pragma unroll
            for (int c = 0; c < 4; c++)
                gload16(gB + (size_t)c*32*D_ + k0 + h*64, &Bs[h*8192 + c*2048 + w*512]);
        }
        __syncthreads();
        #pragma unroll
        for (int h = 0; h < 2; h++) {
            #pragma unroll
            for (int ks = 0; ks < 2; ks++) {
                bf16x8 af[4], bfr[2];
                #pragma unroll
                for (int i = 0; i < 4; i++)
                    af[i] = *(const bf16x8*)&As[h*4096 + (i*16 + l15)*64 + (((ks*4+quad)^sx)*8)];
                #pragma unroll
                for (int j = 0; j < 2; j++)
                    bfr[j] = *(const bf16x8*)&Bs[h*8192 + (nw + j*16 + l15)*64 + (((ks*4+quad)^sx)*8)];
                __builtin_amdgcn_s_setprio(1);
                #pragma unroll
                for (int i = 0; i < 4; i++)
                    #pragma unroll
                    for (int j = 0; j < 2; j++)
                        acc[i][j] = __builtin_amdgcn_mfma_f32_16x16x32_bf16(af[i], bfr[j], acc[i][j], 0, 0, 0);
                __builtin_amdgcn_s_setprio(0);
            }
        }
        __syncthreads();
    }

    #pragma unroll
    for (int j = 0; j < 2; j++) {
        int n = n0 + nw + j*16 + l15;
        float bn = bias[n];
        #pragma unroll
        for (int i = 0; i < 4; i++) {
            int mbase = m0 + i*16 + quad*4;
            #pragma unroll
            for (int r = 0; r < 4; r++)
                Out[(size_t)(mbase + r)*D_ + n] = acc[i][j][r] + bn;
        }
    }
}

// ---------------- fused attention v8r (proven 51.8 us — unchanged) ----------
#define ATT_PAIR(BUFA, K0, PF)                                                  \
  {                                                                             \
    if (PF) {                                                                   \
      const int kp = (K0) + 128;                                                \
      _Pragma("unroll")                                                         \
      for (int c = 0; c < 2; c++) {                                             \
        gload16(KstK + (size_t)(kp + c*32)*HD_,      &Ks[(BUFA)^2][c*2048 + w*512]);     \
        gload16(VstV + (size_t)c*32*S_ + kp,         &Vs[(BUFA)^2][c*2048 + w*512]);     \
        gload16(KstK + (size_t)(kp + 64 + c*32)*HD_, &Ks[((BUFA)^2)+1][c*2048 + w*512]); \
        gload16(VstV + (size_t)c*32*S_ + kp + 64,    &Vs[((BUFA)^2)+1][c*2048 + w*512]); \
      }                                                                         \
    }                                                                           \
    f32x4 st[2][4][2];                                                          \
    _Pragma("unroll")                                                           \
    for (int sub = 0; sub < 2; sub++) {                                         \
      const int kb = (K0) + sub*64;                                             \
      _Pragma("unroll")                                                         \
      for (int g = 0; g < 4; g++) {                                             \
        float4 m4 = *(const float4*)&Ms[kb + quad*8 + (g>>1)*32 + (g&1)*4];     \
        f32x4 sti = (f32x4){m4.x, m4.y, m4.z, m4.w} * 10000.f - 10000.f;        \
        st[sub][g][0] = sti;                                                    \
        st[sub][g][1] = sti;                                                    \
      }                                                                         \
    }                                                                           \
    __builtin_amdgcn_s_setprio(1);                                              \
    _Pragma("unroll")                                                           \
    for (int sub = 0; sub < 2; sub++) {                                         \
      _Pragma("unroll")                                                         \
      for (int ks = 0; ks < 2; ks++) {                                          \
        _Pragma("unroll")                                                       \
        for (int g = 0; g < 4; g++) {                                           \
          const int kk = g >> 1, hf = g & 1;                                    \
          bf16x8 af = *(const bf16x8*)&Ks[(BUFA)+sub][(arow + hf*4 + kk*32)*64 + (((ks*4+quad)^sx)*8)]; \
          _Pragma("unroll")                                                     \
          for (int m2 = 0; m2 < 2; m2++)                                        \
            st[sub][g][m2] = __builtin_amdgcn_mfma_f32_16x16x32_bf16(af, qf[m2][ks], st[sub][g][m2], 0, 0, 0); \
        }                                                                       \
      }                                                                         \
    }                                                                           \
    __builtin_amdgcn_s_setprio(0);                                              \
    _Pragma("unroll")                                                           \
    for (int sub = 0; sub < 2; sub++) {                                         \
      bf16x8 pa[2][2];                                                          \
      _Pragma("unroll")                                                         \
      for (int m2 = 0; m2 < 2; m2++) {                                          \
        _Pragma("unroll")                                                       \
        for (int kk = 0; kk < 2; kk++) {                                        \
          union { bf16 h8[8]; bf16x8 v; } pk;                                   \
          _Pragma("unroll")                                                     \
          for (int hf = 0; hf < 2; hf++) {                                      \
            f32x4 sv = st[sub][kk*2 + hf][m2];                                  \
            f32x2 lo, hi;                                                       \
            lo.x = __builtin_amdgcn_fmed3f(sv[0], -3.f, 3.f);                   \
            lo.y = __builtin_amdgcn_fmed3f(sv[1], -3.f, 3.f);                   \
            hi.x = __builtin_amdgcn_fmed3f(sv[2], -3.f, 3.f);                   \
            hi.y = __builtin_amdgcn_fmed3f(sv[3], -3.f, 3.f);                   \
            f32x2 tlo = lo * lo * (-0.01f) + 0.25f;                             \
            f32x2 thi = hi * hi * (-0.01f) + 0.25f;                             \
            f32x2 slo = lo * tlo + 0.5f;                                        \
            f32x2 shi = hi * thi + 0.5f;                                        \
            lacv[m2] += slo;                                                    \
            lacv[m2] += shi;                                                    \
            pk.h8[hf*4+0] = (bf16)slo.x; pk.h8[hf*4+1] = (bf16)slo.y;           \
            pk.h8[hf*4+2] = (bf16)shi.x; pk.h8[hf*4+3] = (bf16)shi.y;           \
          }                                                                     \
          pa[m2][kk] = pk.v;                                                    \
        }                                                                       \
      }                                                                         \
      _Pragma("unroll")                                                         \
      for (int kk = 0; kk < 2; kk++) {                                          \
        bf16x8 vf[4];                                                           \
        _Pragma("unroll")                                                       \
        for (int nt = 0; nt < 4; nt++)                                          \
          vf[nt] = *(const bf16x8*)&Vs[(BUFA)+sub][(nt*16 + l15)*64 + (((kk*4+quad)^sx)*8)]; \
        __builtin_amdgcn_s_setprio(1);                                          \
        _Pragma("unroll")                                                       \
        for (int m2 = 0; m2 < 2; m2++)                                          \
          _Pragma("unroll")                                                     \
          for (int nt = 0; nt < 4; nt++)                                        \
            cacc[m2][nt] = __builtin_amdgcn_mfma_f32_16x16x32_bf16(pa[m2][kk], vf[nt], cacc[m2][nt], 0, 0, 0); \
        __builtin_amdgcn_s_setprio(0);                                          \
      }                                                                         \
    }                                                                           \
    asm volatile("s_waitcnt vmcnt(0)\n\ts_barrier" ::: "memory");               \
  }

__global__ __launch_bounds__(256, 2) void k_attn(
    const bf16* __restrict__ Q, const bf16* __restrict__ K, const bf16* __restrict__ Vt,
    const float* __restrict__ mask, bf16* __restrict__ Ctx)
{
    const int bh = blockIdx.y;
    const int b = bh >> 4, h = bh & 15;
    const int q0 = blockIdx.x * 128;
    const int t = threadIdx.x;
    const int w = t >> 6, lane = t & 63, quad = lane >> 4, l15 = lane & 15;
    const int lr = lane >> 3;
    const int lcV = (lane & 7) ^ lr;                          // Vs swizzle: row&7
    const int lcK = (lane & 7) ^ ((lr & 3) | ((w & 1) << 2)); // Ks swizzle: row bits {0,1,3}
    const int sx = l15 & 7;
    const int arow = ((l15 & 12) << 1) | (l15 & 3);           // bit-spread A-row base

    __shared__ __align__(16) bf16 Ks[4][64*64];   // 32 KB
    __shared__ __align__(16) bf16 Vs[4][64*64];   // 32 KB
    __shared__ __align__(16) float Ms[S_];        //  8 KB mask row for batch b

    // Q B-frags for this wave's 32 q-rows (4 frags, 16 VGPRs)
    bf16x8 qf[2][2];
    const bf16* Qbase = Q + ((size_t)bh*S_ + q0 + w*32)*HD_;
    #pragma unroll
    for (int m2 = 0; m2 < 2; m2++)
        #pragma unroll
        for (int ks = 0; ks < 2; ks++)
            qf[m2][ks] = *(const bf16x8*)&Qbase[(size_t)(m2*16 + l15)*HD_ + ks*32 + quad*8];

    f32x4 cacc[2][4];
    #pragma unroll
    for (int i = 0; i < 2; i++)
        #pragma unroll
        for (int j = 0; j < 4; j++)
            cacc[i][j] = (f32x4){0.f,0.f,0.f,0.f};
    f32x2 lacv[2];
    #pragma unroll
    for (int m2 = 0; m2 < 2; m2++) lacv[m2] = (f32x2){0.f,0.f};

    const bf16* KstK = K  + ((size_t)bh*S_  + w*8 + lr)*HD_ + lcK*8;
    const bf16* VstV = Vt + ((size_t)bh*HD_ + w*8 + lr)*S_  + lcV*8;

    // ---- prologue: mask row -> LDS; stage tiles 0,1 into bufs 0,1 ----
    {
        const float* mg = mask + (size_t)b*S_ + t*8;
        float4 a0 = *(const float4*)mg;
        float4 a1 = *(const float4*)(mg + 4);
        *(float4*)&Ms[t*8]     = a0;
        *(float4*)&Ms[t*8 + 4] = a1;
    }
    #pragma unroll
    for (int c = 0; c < 2; c++) {
        gload16(KstK + (size_t)(c*32)*HD_,      &Ks[0][c*2048 + w*512]);
        gload16(VstV + (size_t)c*32*S_,         &Vs[0][c*2048 + w*512]);
        gload16(KstK + (size_t)(64 + c*32)*HD_, &Ks[1][c*2048 + w*512]);
        gload16(VstV + (size_t)c*32*S_ + 64,    &Vs[1][c*2048 + w*512]);
    }
    asm volatile("s_waitcnt vmcnt(0) lgkmcnt(0)\n\ts_barrier" ::: "memory");

    // main loop: 16 pairs, alternating buffer sets {0,1} / {2,3}
    for (int q2 = 0; q2 < S_/256; q2++) {       // 8 outer iterations
        const int k0 = q2 * 256;
        ATT_PAIR(0, k0,        true);
        ATT_PAIR(2, k0 + 128,  (q2 < S_/256 - 1));
    }

    // epilogue: row-sums fully within the wave (quads hold disjoint k subsets)
    float s[2];
    #pragma unroll
    for (int m2 = 0; m2 < 2; m2++) {
        float v = lacv[m2].x + lacv[m2].y;
        v += __shfl_xor(v, 16);
        v += __shfl_xor(v, 32);
        s[m2] = v;   // lane l now holds rowsum for q = m2*16 + (l&15)
    }

    #pragma unroll
    for (int m2 = 0; m2 < 2; m2++) {
        #pragma unroll
        for (int r = 0; r < 4; r++) {
            float rs = __shfl(s[m2], quad*4 + r);   // redistribute l15-indexed -> row-indexed
            float rinv = 1.0f / (rs + 1e-8f);
            size_t row = (size_t)(b*S_ + q0 + w*32 + m2*16 + quad*4 + r);
            #pragma unroll
            for (int nt = 0; nt < 4; nt++)
                Ctx[row*D_ + h*HD_ + nt*16 + l15] = (bf16)(cacc[m2][nt][r] * rinv);
        }
    }
}

extern "C" void kernel_launch(void* const* d_in, const int* in_sizes, int n_in,
                              void* d_out, int out_size, void* d_ws, size_t ws_size,
                              hipStream_t stream) {
    const float* hs   = (const float*)d_in[0];
    const float* mask = (const float*)d_in[1];
    const float* Wq   = (const float*)d_in[2];
    const float* bq   = (const float*)d_in[3];
    const float* Wk   = (const float*)d_in[4];
    const float* bk   = (const float*)d_in[5];
    const float* Wv   = (const float*)d_in[6];
    const float* bv   = (const float*)d_in[7];
    const float* Wo   = (const float*)d_in[8];
    const float* bo   = (const float*)d_in[9];
    float* out = (float*)d_out;

    char* ws = (char*)d_ws;
    const size_t MB = 1024*1024;
    bf16* hb   = (bf16*)(ws);            // [M_,D_]        8 MB
    bf16* wqb  = (bf16*)(ws + 8*MB);     // [D_,D_]        2 MB
    bf16* wkb  = (bf16*)(ws + 10*MB);
    bf16* wvb  = (bf16*)(ws + 12*MB);
    bf16* wob  = (bf16*)(ws + 14*MB);
    bf16* qb   = (bf16*)(ws + 16*MB);    // [BH][S][HD]    8 MB
    bf16* kb   = (bf16*)(ws + 24*MB);    // [BH][S][HD]    8 MB
    bf16* vtb  = (bf16*)(ws + 32*MB);    // [BH][HD][S]    8 MB
    bf16* ctxb = (bf16*)(ws + 40*MB);    // [M_,D_]        8 MB

    k_cvt_all<<<2048 + 4*512, 256, 0, stream>>>(hs, Wq, Wk, Wv, Wo, hb, wqb, wkb, wvb, wob);

    k_gemm_qkv<<<dim3(H_, M_/128), 256, 0, stream>>>(
        hb, wqb, wkb, wvb, bq, bk, bv, qb, kb, vtb);

    k_attn<<<dim3(S_/128, B_*H_), 256, 0, stream>>>(qb, kb, vtb, mask, ctxb);

    k_gemm_out<<<dim3(D_/128, M_/64), 256, 0, stream>>>(ctxb, wob, bo, out);
}

// Round 10
// 188.428 us; speedup vs baseline: 1.0604x; 1.0604x over previous
//
#include <hip/hip_runtime.h>
#include <stdint.h>

#define B_ 2
#define S_ 2048
#define D_ 1024
#define H_ 16
#define HD_ 64
#define M_ (B_*S_)   // 4096

typedef __bf16 bf16;
typedef __attribute__((ext_vector_type(8))) __bf16 bf16x8;
typedef __attribute__((ext_vector_type(4))) float f32x4;
typedef __attribute__((ext_vector_type(2))) float f32x2;

// async global->LDS, 16B per lane. LDS dest = uniform base + lane*16.
__device__ __forceinline__ void gload16(const bf16* g, bf16* l) {
    __builtin_amdgcn_global_load_lds(
        (const __attribute__((address_space(1))) void*)g,
        (__attribute__((address_space(3))) void*)l, 16, 0, 0);
}

// ---------------- fp32 -> bf16 converts (single launch) ----------------
__global__ void k_cvt_all(const float* __restrict__ hs,
                          const float* __restrict__ Wq, const float* __restrict__ Wk,
                          const float* __restrict__ Wv, const float* __restrict__ Wo,
                          bf16* __restrict__ hb,
                          bf16* __restrict__ wqb, bf16* __restrict__ wkb,
                          bf16* __restrict__ wvb, bf16* __restrict__ wob) {
    int blk = blockIdx.x;
    const float* s; bf16* d; int base;
    if (blk < 2048) { s = hs; d = hb; base = blk; }
    else {
        int r = blk - 2048; int which = r >> 9; base = r & 511;
        s = (which==0)?Wq:(which==1)?Wk:(which==2)?Wv:Wo;
        d = (which==0)?wqb:(which==1)?wkb:(which==2)?wvb:wob;
    }
    int idx = base*2048 + threadIdx.x*8;
    float4 a = *(const float4*)(s + idx);
    float4 b = *(const float4*)(s + idx + 4);
    bf16 o[8] = {(bf16)a.x,(bf16)a.y,(bf16)a.z,(bf16)a.w,
                 (bf16)b.x,(bf16)b.y,(bf16)b.z,(bf16)b.w};
    *(int4*)(d + idx) = *(const int4*)o;
}

// ---------------- fused QKV projection GEMM (z-fused, BM=64, 4 blocks/CU) ----
// r7's z-fused structure (best measured) with the m-tile halved: BM 128->64,
// grid (16,64)=1024 blocks, LDS 32 KB -> 4 blocks/CU (was 2 lockstep blocks).
// Per-wave per-iter: 8 DMAs + 8 ds_read_b128 + 24 MFMA. Probes the one
// un-tested GEMM axis: block-level parallelism. A/B re-reads stay L3-resident
// (v9's doubled-HBM failure mode does not apply).
__global__ __launch_bounds__(256, 4) void k_gemm_qkv(
    const bf16* __restrict__ X,
    const bf16* __restrict__ Wq, const bf16* __restrict__ Wk, const bf16* __restrict__ Wv,
    const float* __restrict__ bq, const float* __restrict__ bk, const float* __restrict__ bv,
    bf16* __restrict__ Qo, bf16* __restrict__ Ko, bf16* __restrict__ Vo)
{
    const int hh = blockIdx.x;           // head = n-tile (64-aligned)
    const int n0 = hh * 64;
    const int m0 = blockIdx.y * 64;
    const int t = threadIdx.x;
    const int w = t >> 6, lane = t & 63, quad = lane >> 4, l15 = lane & 15;
    const int lr = lane >> 3;
    const int lc = (lane & 7) ^ lr;
    const int sx = l15 & 7;
    const int mw = (w >> 1) * 32, nw = (w & 1) * 32;

    __shared__ __align__(16) char smraw[32768];  // As 8K + Bsf 24K; epi aliases
    bf16* As  = (bf16*)smraw;               // [64][64]
    bf16* Bsf = (bf16*)(smraw + 8192);      // [3][64][64]
    bf16* epi = (bf16*)smraw;               // [64][72]

    f32x4 acc[3][2][2];
    #pragma unroll
    for (int z = 0; z < 3; z++)
        #pragma unroll
        for (int i = 0; i < 2; i++)
            #pragma unroll
            for (int j = 0; j < 2; j++)
                acc[z][i][j] = (f32x4){0.f,0.f,0.f,0.f};

    const bf16* gA = X + (size_t)(m0 + w*8 + lr)*D_ + lc*8;
    const bf16* Wz[3] = {Wq, Wk, Wv};
    const bf16* gB[6];
    #pragma unroll
    for (int cc = 0; cc < 6; cc++) {
        const int z = cc >> 1;
        const int rowz = (cc & 1)*32 + w*8 + lr;
        gB[cc] = Wz[z] + (size_t)(n0 + rowz)*D_ + lc*8;
    }

    for (int k0 = 0; k0 < D_; k0 += 64) {
        #pragma unroll
        for (int c = 0; c < 2; c++)
            gload16(gA + (size_t)c*32*D_ + k0, &As[c*2048 + w*512]);
        #pragma unroll
        for (int cc = 0; cc < 6; cc++)
            gload16(gB[cc] + k0, &Bsf[cc*2048 + w*512]);
        __syncthreads();
        #pragma unroll
        for (int ks = 0; ks < 2; ks++) {
            bf16x8 af[2], bfr[3][2];
            #pragma unroll
            for (int i = 0; i < 2; i++)
                af[i] = *(const bf16x8*)&As[(mw + i*16 + l15)*64 + (((ks*4+quad)^sx)*8)];
            #pragma unroll
            for (int z = 0; z < 3; z++)
                #pragma unroll
                for (int j = 0; j < 2; j++)
                    bfr[z][j] = *(const bf16x8*)&Bsf[z*4096 + (nw + j*16 + l15)*64 + (((ks*4+quad)^sx)*8)];
            __builtin_amdgcn_s_setprio(1);
            #pragma unroll
            for (int z = 0; z < 3; z++)
                #pragma unroll
                for (int i = 0; i < 2; i++)
                    #pragma unroll
                    for (int j = 0; j < 2; j++)
                        acc[z][i][j] = __builtin_amdgcn_mfma_f32_16x16x32_bf16(af[i], bfr[z][j], acc[z][i][j], 0, 0, 0);
            __builtin_amdgcn_s_setprio(0);
        }
        __syncthreads();
    }

    // ---- epilogues (per z, sequential through the aliased epi buffer) ----
    // z = 0 (Q, scale 1/8) and z = 1 (K): epi[m=64][stride 72], row-coalesced store
    #pragma unroll
    for (int z = 0; z < 2; z++) {
        const float scale = z ? 1.0f : 0.125f;
        const float* bias = z ? bk : bq;
        bf16* Out = z ? Ko : Qo;
        #pragma unroll
        for (int j = 0; j < 2; j++) {
            int n = nw + j*16 + l15;
            float bn = bias[n0 + n];
            #pragma unroll
            for (int i = 0; i < 2; i++) {
                int mloc = mw + i*16 + quad*4;
                #pragma unroll
                for (int r = 0; r < 4; r++)
                    epi[(mloc + r)*72 + n] = (bf16)((acc[z][i][j][r] + bn) * scale);
            }
        }
        __syncthreads();
        #pragma unroll
        for (int p = 0; p < 2; p++) {
            int c = t + 256*p;
            int row = c >> 3;             // local m (0..63)
            int ncol = (c & 7) * 8;       // local n (hd)
            int4 val = *(const int4*)&epi[row*72 + ncol];
            int m = m0 + row; int bb = m >> 11, s = m & 2047;
            *(int4*)&Out[((size_t)((bb*H_ + hh)*S_ + s))*HD_ + ncol] = val;
        }
        __syncthreads();
    }
    // z = 2 (V): epi[n=64][m stride 72], m-coalesced (transposed) store
    {
        #pragma unroll
        for (int j = 0; j < 2; j++) {
            int n = nw + j*16 + l15;
            float bn = bv[n0 + n];
            #pragma unroll
            for (int i = 0; i < 2; i++) {
                int mloc = mw + i*16 + quad*4;
                union { bf16 h4[4]; uint2 u; } pk;
                #pragma unroll
                for (int r = 0; r < 4; r++) pk.h4[r] = (bf16)(acc[2][i][j][r] + bn);
                *(uint2*)&epi[n*72 + mloc] = pk.u;
            }
        }
        __syncthreads();
        #pragma unroll
        for (int p = 0; p < 2; p++) {
            int c = t + 256*p;
            int row = c >> 3;             // local n (hd, 0..63)
            int mcol = (c & 7) * 8;       // local m (token)
            int4 val = *(const int4*)&epi[row*72 + mcol];
            int m = m0 + mcol; int bb = m >> 11, s = m & 2047;
            *(int4*)&Vo[((size_t)((bb*H_ + hh)*HD_ + row))*S_ + s] = val;
        }
    }
}

// ---------------- output projection GEMM (64x128 tile) — r7 version ----------
__global__ __launch_bounds__(256) void k_gemm_out(
    const bf16* __restrict__ X, const bf16* __restrict__ W,
    const float* __restrict__ bias, float* __restrict__ Out)
{
    const int n0 = blockIdx.x * 128;
    const int m0 = blockIdx.y * 64;
    const int t = threadIdx.x;
    const int w = t >> 6, lane = t & 63, quad = lane >> 4, l15 = lane & 15;
    const int lr = lane >> 3;
    const int lc = (lane & 7) ^ lr;
    const int sx = l15 & 7;
    const int nw = w * 32;

    __shared__ __align__(16) bf16 As[64*64];
    __shared__ __align__(16) bf16 Bs[128*64];

    f32x4 acc[4][2];
    #pragma unroll
    for (int i = 0; i < 4; i++)
        #pragma unroll
        for (int j = 0; j < 2; j++)
            acc[i][j] = (f32x4){0.f,0.f,0.f,0.f};

    const bf16* gA = X + (size_t)(m0 + w*8 + lr)*D_ + lc*8;
    const bf16* gB = W + (size_t)(n0 + w*8 + lr)*D_ + lc*8;

    for (int k0 = 0; k0 < D_; k0 += 64) {
        #pragma unroll
        for (int c = 0; c < 2; c++)
            gload16(gA + (size_t)c*32*D_ + k0, &As[c*2048 + w*512]);
        #pragma unroll
        for (int c = 0; c < 4; c++)
            gload16(gB + (size_t)c*32*D_ + k0, &Bs[c*2048 + w*512]);
        __syncthreads();
        #pragma unroll
        for (int ks = 0; ks < 2; ks++) {
            bf16x8 af[4], bfr[2];
            #pragma unroll
            for (int i = 0; i < 4; i++)
                af[i] = *(const bf16x8*)&As[(i*16 + l15)*64 + (((ks*4+quad)^sx)*8)];
            #pragma unroll
            for (int j = 0; j < 2; j++)
                bfr[j] = *(const bf16x8*)&Bs[(nw + j*16 + l15)*64 + (((ks*4+quad)^sx)*8)];
            #pragma unroll
            for (int i = 0; i < 4; i++)
                #pragma unroll
                for (int j = 0; j < 2; j++)
                    acc[i][j] = __builtin_amdgcn_mfma_f32_16x16x32_bf16(af[i], bfr[j], acc[i][j], 0, 0, 0);
        }
        __syncthreads();
    }

    #pragma unroll
    for (int j = 0; j < 2; j++) {
        int n = n0 + nw + j*16 + l15;
        float bn = bias[n];
        #pragma unroll
        for (int i = 0; i < 4; i++) {
            int mbase = m0 + i*16 + quad*4;
            #pragma unroll
            for (int r = 0; r < 4; r++)
                Out[(size_t)(mbase + r)*D_ + n] = acc[i][j][r] + bn;
        }
    }
}

// ---------------- fused attention v8r (proven 51.9 us — unchanged) ----------
#define ATT_PAIR(BUFA, K0, PF)                                                  \
  {                                                                             \
    if (PF) {                                                                   \
      const int kp = (K0) + 128;                                                \
      _Pragma("unroll")                                                         \
      for (int c = 0; c < 2; c++) {                                             \
        gload16(KstK + (size_t)(kp + c*32)*HD_,      &Ks[(BUFA)^2][c*2048 + w*512]);     \
        gload16(VstV + (size_t)c*32*S_ + kp,         &Vs[(BUFA)^2][c*2048 + w*512]);     \
        gload16(KstK + (size_t)(kp + 64 + c*32)*HD_, &Ks[((BUFA)^2)+1][c*2048 + w*512]); \
        gload16(VstV + (size_t)c*32*S_ + kp + 64,    &Vs[((BUFA)^2)+1][c*2048 + w*512]); \
      }                                                                         \
    }                                                                           \
    f32x4 st[2][4][2];                                                          \
    _Pragma("unroll")                                                           \
    for (int sub = 0; sub < 2; sub++) {                                         \
      const int kb = (K0) + sub*64;                                             \
      _Pragma("unroll")                                                         \
      for (int g = 0; g < 4; g++) {                                             \
        float4 m4 = *(const float4*)&Ms[kb + quad*8 + (g>>1)*32 + (g&1)*4];     \
        f32x4 sti = (f32x4){m4.x, m4.y, m4.z, m4.w} * 10000.f - 10000.f;        \
        st[sub][g][0] = sti;                                                    \
        st[sub][g][1] = sti;                                                    \
      }                                                                         \
    }                                                                           \
    __builtin_amdgcn_s_setprio(1);                                              \
    _Pragma("unroll")                                                           \
    for (int sub = 0; sub < 2; sub++) {                                         \
      _Pragma("unroll")                                                         \
      for (int ks = 0; ks < 2; ks++) {                                          \
        _Pragma("unroll")                                                       \
        for (int g = 0; g < 4; g++) {                                           \
          const int kk = g >> 1, hf = g & 1;                                    \
          bf16x8 af = *(const bf16x8*)&Ks[(BUFA)+sub][(arow + hf*4 + kk*32)*64 + (((ks*4+quad)^sx)*8)]; \
          _Pragma("unroll")                                                     \
          for (int m2 = 0; m2 < 2; m2++)                                        \
            st[sub][g][m2] = __builtin_amdgcn_mfma_f32_16x16x32_bf16(af, qf[m2][ks], st[sub][g][m2], 0, 0, 0); \
        }                                                                       \
      }                                                                         \
    }                                                                           \
    __builtin_amdgcn_s_setprio(0);                                              \
    _Pragma("unroll")                                                           \
    for (int sub = 0; sub < 2; sub++) {                                         \
      bf16x8 pa[2][2];                                                          \
      _Pragma("unroll")                                                         \
      for (int m2 = 0; m2 < 2; m2++) {                                          \
        _Pragma("unroll")                                                       \
        for (int kk = 0; kk < 2; kk++) {                                        \
          union { bf16 h8[8]; bf16x8 v; } pk;                                   \
          _Pragma("unroll")                                                     \
          for (int hf = 0; hf < 2; hf++) {                                      \
            f32x4 sv = st[sub][kk*2 + hf][m2];                                  \
            f32x2 lo, hi;                                                       \
            lo.x = __builtin_amdgcn_fmed3f(sv[0], -3.f, 3.f);                   \
            lo.y = __builtin_amdgcn_fmed3f(sv[1], -3.f, 3.f);                   \
            hi.x = __builtin_amdgcn_fmed3f(sv[2], -3.f, 3.f);                   \
            hi.y = __builtin_amdgcn_fmed3f(sv[3], -3.f, 3.f);                   \
            f32x2 tlo = lo * lo * (-0.01f) + 0.25f;                             \
            f32x2 thi = hi * hi * (-0.01f) + 0.25f;                             \
            f32x2 slo = lo * tlo + 0.5f;                                        \
            f32x2 shi = hi * thi + 0.5f;                                        \
            lacv[m2] += slo;                                                    \
            lacv[m2] += shi;                                                    \
            pk.h8[hf*4+0] = (bf16)slo.x; pk.h8[hf*4+1] = (bf16)slo.y;           \
            pk.h8[hf*4+2] = (bf16)shi.x; pk.h8[hf*4+3] = (bf16)shi.y;           \
          }                                                                     \
          pa[m2][kk] = pk.v;                                                    \
        }                                                                       \
      }                                                                         \
      _Pragma("unroll")                                                         \
      for (int kk = 0; kk < 2; kk++) {                                          \
        bf16x8 vf[4];                                                           \
        _Pragma("unroll")                                                       \
        for (int nt = 0; nt < 4; nt++)                                          \
          vf[nt] = *(const bf16x8*)&Vs[(BUFA)+sub][(nt*16 + l15)*64 + (((kk*4+quad)^sx)*8)]; \
        __builtin_amdgcn_s_setprio(1);                                          \
        _Pragma("unroll")                                                       \
        for (int m2 = 0; m2 < 2; m2++)                                          \
          _Pragma("unroll")                                                     \
          for (int nt = 0; nt < 4; nt++)                                        \
            cacc[m2][nt] = __builtin_amdgcn_mfma_f32_16x16x32_bf16(pa[m2][kk], vf[nt], cacc[m2][nt], 0, 0, 0); \
        __builtin_amdgcn_s_setprio(0);                                          \
      }                                                                         \
    }                                                                           \
    asm volatile("s_waitcnt vmcnt(0)\n\ts_barrier" ::: "memory");               \
  }

__global__ __launch_bounds__(256, 2) void k_attn(
    const bf16* __restrict__ Q, const bf16* __restrict__ K, const bf16* __restrict__ Vt,
    const float* __restrict__ mask, bf16* __restrict__ Ctx)
{
    const int bh = blockIdx.y;
    const int b = bh >> 4, h = bh & 15;
    const int q0 = blockIdx.x * 128;
    const int t = threadIdx.x;
    const int w = t >> 6, lane = t & 63, quad = lane >> 4, l15 = lane & 15;
    const int lr = lane >> 3;
    const int lcV = (lane & 7) ^ lr;                          // Vs swizzle: row&7
    const int lcK = (lane & 7) ^ ((lr & 3) | ((w & 1) << 2)); // Ks swizzle: row bits {0,1,3}
    const int sx = l15 & 7;
    const int arow = ((l15 & 12) << 1) | (l15 & 3);           // bit-spread A-row base

    __shared__ __align__(16) bf16 Ks[4][64*64];   // 32 KB
    __shared__ __align__(16) bf16 Vs[4][64*64];   // 32 KB
    __shared__ __align__(16) float Ms[S_];        //  8 KB mask row for batch b

    // Q B-frags for this wave's 32 q-rows (4 frags, 16 VGPRs)
    bf16x8 qf[2][2];
    const bf16* Qbase = Q + ((size_t)bh*S_ + q0 + w*32)*HD_;
    #pragma unroll
    for (int m2 = 0; m2 < 2; m2++)
        #pragma unroll
        for (int ks = 0; ks < 2; ks++)
            qf[m2][ks] = *(const bf16x8*)&Qbase[(size_t)(m2*16 + l15)*HD_ + ks*32 + quad*8];

    f32x4 cacc[2][4];
    #pragma unroll
    for (int i = 0; i < 2; i++)
        #pragma unroll
        for (int j = 0; j < 4; j++)
            cacc[i][j] = (f32x4){0.f,0.f,0.f,0.f};
    f32x2 lacv[2];
    #pragma unroll
    for (int m2 = 0; m2 < 2; m2++) lacv[m2] = (f32x2){0.f,0.f};

    const bf16* KstK = K  + ((size_t)bh*S_  + w*8 + lr)*HD_ + lcK*8;
    const bf16* VstV = Vt + ((size_t)bh*HD_ + w*8 + lr)*S_  + lcV*8;

    // ---- prologue: mask row -> LDS; stage tiles 0,1 into bufs 0,1 ----
    {
        const float* mg = mask + (size_t)b*S_ + t*8;
        float4 a0 = *(const float4*)mg;
        float4 a1 = *(const float4*)(mg + 4);
        *(float4*)&Ms[t*8]     = a0;
        *(float4*)&Ms[t*8 + 4] = a1;
    }
    #pragma unroll
    for (int c = 0; c < 2; c++) {
        gload16(KstK + (size_t)(c*32)*HD_,      &Ks[0][c*2048 + w*512]);
        gload16(VstV + (size_t)c*32*S_,         &Vs[0][c*2048 + w*512]);
        gload16(KstK + (size_t)(64 + c*32)*HD_, &Ks[1][c*2048 + w*512]);
        gload16(VstV + (size_t)c*32*S_ + 64,    &Vs[1][c*2048 + w*512]);
    }
    asm volatile("s_waitcnt vmcnt(0) lgkmcnt(0)\n\ts_barrier" ::: "memory");

    // main loop: 16 pairs, alternating buffer sets {0,1} / {2,3}
    for (int q2 = 0; q2 < S_/256; q2++) {       // 8 outer iterations
        const int k0 = q2 * 256;
        ATT_PAIR(0, k0,        true);
        ATT_PAIR(2, k0 + 128,  (q2 < S_/256 - 1));
    }

    // epilogue: row-sums fully within the wave (quads hold disjoint k subsets)
    float s[2];
    #pragma unroll
    for (int m2 = 0; m2 < 2; m2++) {
        float v = lacv[m2].x + lacv[m2].y;
        v += __shfl_xor(v, 16);
        v += __shfl_xor(v, 32);
        s[m2] = v;   // lane l now holds rowsum for q = m2*16 + (l&15)
    }

    #pragma unroll
    for (int m2 = 0; m2 < 2; m2++) {
        #pragma unroll
        for (int r = 0; r < 4; r++) {
            float rs = __shfl(s[m2], quad*4 + r);   // redistribute l15-indexed -> row-indexed
            float rinv = 1.0f / (rs + 1e-8f);
            size_t row = (size_t)(b*S_ + q0 + w*32 + m2*16 + quad*4 + r);
            #pragma unroll
            for (int nt = 0; nt < 4; nt++)
                Ctx[row*D_ + h*HD_ + nt*16 + l15] = (bf16)(cacc[m2][nt][r] * rinv);
        }
    }
}

extern "C" void kernel_launch(void* const* d_in, const int* in_sizes, int n_in,
                              void* d_out, int out_size, void* d_ws, size_t ws_size,
                              hipStream_t stream) {
    const float* hs   = (const float*)d_in[0];
    const float* mask = (const float*)d_in[1];
    const float* Wq   = (const float*)d_in[2];
    const float* bq   = (const float*)d_in[3];
    const float* Wk   = (const float*)d_in[4];
    const float* bk   = (const float*)d_in[5];
    const float* Wv   = (const float*)d_in[6];
    const float* bv   = (const float*)d_in[7];
    const float* Wo   = (const float*)d_in[8];
    const float* bo   = (const float*)d_in[9];
    float* out = (float*)d_out;

    char* ws = (char*)d_ws;
    const size_t MB = 1024*1024;
    bf16* hb   = (bf16*)(ws);            // [M_,D_]        8 MB
    bf16* wqb  = (bf16*)(ws + 8*MB);     // [D_,D_]        2 MB
    bf16* wkb  = (bf16*)(ws + 10*MB);
    bf16* wvb  = (bf16*)(ws + 12*MB);
    bf16* wob  = (bf16*)(ws + 14*MB);
    bf16* qb   = (bf16*)(ws + 16*MB);    // [BH][S][HD]    8 MB
    bf16* kb   = (bf16*)(ws + 24*MB);    // [BH][S][HD]    8 MB
    bf16* vtb  = (bf16*)(ws + 32*MB);    // [BH][HD][S]    8 MB
    bf16* ctxb = (bf16*)(ws + 40*MB);    // [M_,D_]        8 MB

    k_cvt_all<<<2048 + 4*512, 256, 0, stream>>>(hs, Wq, Wk, Wv, Wo, hb, wqb, wkb, wvb, wob);

    k_gemm_qkv<<<dim3(H_, M_/64), 256, 0, stream>>>(
        hb, wqb, wkb, wvb, bq, bk, bv, qb, kb, vtb);

    k_attn<<<dim3(S_/128, B_*H_), 256, 0, stream>>>(qb, kb, vtb, mask, ctxb);

    k_gemm_out<<<dim3(D_/128, M_/64), 256, 0, stream>>>(ctxb, wob, bo, out);
}

// Round 11
// 183.648 us; speedup vs baseline: 1.0880x; 1.0260x over previous
//
#include <hip/hip_runtime.h>
#include <stdint.h>

#define B_ 2
#define S_ 2048
#define D_ 1024
#define H_ 16
#define HD_ 64
#define M_ (B_*S_)   // 4096

typedef __bf16 bf16;
typedef __attribute__((ext_vector_type(8))) __bf16 bf16x8;
typedef __attribute__((ext_vector_type(4))) float f32x4;
typedef __attribute__((ext_vector_type(2))) float f32x2;

// async global->LDS, 16B per lane. LDS dest = uniform base + lane*16.
__device__ __forceinline__ void gload16(const bf16* g, bf16* l) {
    __builtin_amdgcn_global_load_lds(
        (const __attribute__((address_space(1))) void*)g,
        (__attribute__((address_space(3))) void*)l, 16, 0, 0);
}

// ---------------- fp32 -> bf16 converts (single launch) ----------------
__global__ void k_cvt_all(const float* __restrict__ hs,
                          const float* __restrict__ Wq, const float* __restrict__ Wk,
                          const float* __restrict__ Wv, const float* __restrict__ Wo,
                          bf16* __restrict__ hb,
                          bf16* __restrict__ wqb, bf16* __restrict__ wkb,
                          bf16* __restrict__ wvb, bf16* __restrict__ wob) {
    int blk = blockIdx.x;
    const float* s; bf16* d; int base;
    if (blk < 2048) { s = hs; d = hb; base = blk; }
    else {
        int r = blk - 2048; int which = r >> 9; base = r & 511;
        s = (which==0)?Wq:(which==1)?Wk:(which==2)?Wv:Wo;
        d = (which==0)?wqb:(which==1)?wkb:(which==2)?wvb:wob;
    }
    int idx = base*2048 + threadIdx.x*8;
    float4 a = *(const float4*)(s + idx);
    float4 b = *(const float4*)(s + idx + 4);
    bf16 o[8] = {(bf16)a.x,(bf16)a.y,(bf16)a.z,(bf16)a.w,
                 (bf16)b.x,(bf16)b.y,(bf16)b.z,(bf16)b.w};
    *(int4*)(d + idx) = *(const int4*)o;
}

// ---------------- fused QKV projection GEMM (z-fused, BM=128) — r7 best ------
// One block computes Q, K and V for its (m-panel, head) pair: A[128x64k]
// staged once serves 3 weight tiles [64n x 64k]. Per wave-step: 10 gload16 +
// 10 ds_read_b128 -> 48 MFMA. Measured best (186.8 us total). Pipeline
// variants all regressed or neutral: dbuf (r8, +5us), BK=128 (r9, +13us),
// BM=64/4-blocks (r10, +1.6us) -> this simple 2-barrier loop is the optimum
// for this L2-resident GEMM.
__global__ __launch_bounds__(256) void k_gemm_qkv(
    const bf16* __restrict__ X,
    const bf16* __restrict__ Wq, const bf16* __restrict__ Wk, const bf16* __restrict__ Wv,
    const float* __restrict__ bq, const float* __restrict__ bk, const float* __restrict__ bv,
    bf16* __restrict__ Qo, bf16* __restrict__ Ko, bf16* __restrict__ Vo)
{
    const int hh = blockIdx.x;           // head = n-tile (64-aligned)
    const int n0 = hh * 64;
    const int m0 = blockIdx.y * 128;
    const int t = threadIdx.x;
    const int w = t >> 6, lane = t & 63, quad = lane >> 4, l15 = lane & 15;
    const int lr = lane >> 3;
    const int lc = (lane & 7) ^ lr;
    const int sx = l15 & 7;
    const int mw = (w >> 1) * 64, nw = (w & 1) * 32;

    __shared__ __align__(16) char smraw[40960];  // As 16K + Bsf 24K; epi aliases
    bf16* As  = (bf16*)smraw;               // [128][64]
    bf16* Bsf = (bf16*)(smraw + 16384);     // [3][64][64]
    bf16* epi = (bf16*)smraw;               // [128][72] or [64][136]

    f32x4 acc[3][4][2];
    #pragma unroll
    for (int z = 0; z < 3; z++)
        #pragma unroll
        for (int i = 0; i < 4; i++)
            #pragma unroll
            for (int j = 0; j < 2; j++)
                acc[z][i][j] = (f32x4){0.f,0.f,0.f,0.f};

    const bf16* gA = X + (size_t)(m0 + w*8 + lr)*D_ + lc*8;
    const bf16* Wz[3] = {Wq, Wk, Wv};
    const bf16* gB[6];
    #pragma unroll
    for (int cc = 0; cc < 6; cc++) {
        const int z = cc >> 1;
        const int rowz = (cc & 1)*32 + w*8 + lr;
        gB[cc] = Wz[z] + (size_t)(n0 + rowz)*D_ + lc*8;
    }

    for (int k0 = 0; k0 < D_; k0 += 64) {
        #pragma unroll
        for (int c = 0; c < 4; c++)
            gload16(gA + (size_t)c*32*D_ + k0, &As[c*2048 + w*512]);
        #pragma unroll
        for (int cc = 0; cc < 6; cc++)
            gload16(gB[cc] + k0, &Bsf[cc*2048 + w*512]);
        __syncthreads();
        #pragma unroll
        for (int ks = 0; ks < 2; ks++) {
            bf16x8 af[4], bfr[3][2];
            #pragma unroll
            for (int i = 0; i < 4; i++)
                af[i] = *(const bf16x8*)&As[(mw + i*16 + l15)*64 + (((ks*4+quad)^sx)*8)];
            #pragma unroll
            for (int z = 0; z < 3; z++)
                #pragma unroll
                for (int j = 0; j < 2; j++)
                    bfr[z][j] = *(const bf16x8*)&Bsf[z*4096 + (nw + j*16 + l15)*64 + (((ks*4+quad)^sx)*8)];
            #pragma unroll
            for (int z = 0; z < 3; z++)
                #pragma unroll
                for (int i = 0; i < 4; i++)
                    #pragma unroll
                    for (int j = 0; j < 2; j++)
                        acc[z][i][j] = __builtin_amdgcn_mfma_f32_16x16x32_bf16(af[i], bfr[z][j], acc[z][i][j], 0, 0, 0);
        }
        __syncthreads();
    }

    // ---- epilogues (per z, sequential through the aliased epi buffer) ----
    // z = 0 (Q, scale 1/8) and z = 1 (K): epi[m=128][stride 72], row-coalesced store
    #pragma unroll
    for (int z = 0; z < 2; z++) {
        const float scale = z ? 1.0f : 0.125f;
        const float* bias = z ? bk : bq;
        bf16* Out = z ? Ko : Qo;
        #pragma unroll
        for (int j = 0; j < 2; j++) {
            int n = nw + j*16 + l15;
            float bn = bias[n0 + n];
            #pragma unroll
            for (int i = 0; i < 4; i++) {
                int mloc = mw + i*16 + quad*4;
                #pragma unroll
                for (int r = 0; r < 4; r++)
                    epi[(mloc + r)*72 + n] = (bf16)((acc[z][i][j][r] + bn) * scale);
            }
        }
        __syncthreads();
        #pragma unroll
        for (int p = 0; p < 4; p++) {
            int c = t + 256*p;
            int row = c >> 3;             // local m
            int ncol = (c & 7) * 8;       // local n (hd)
            int4 val = *(const int4*)&epi[row*72 + ncol];
            int m = m0 + row; int bb = m >> 11, s = m & 2047;
            *(int4*)&Out[((size_t)((bb*H_ + hh)*S_ + s))*HD_ + ncol] = val;
        }
        __syncthreads();
    }
    // z = 2 (V): epi[n=64][m stride 136], m-coalesced (transposed) store
    {
        #pragma unroll
        for (int j = 0; j < 2; j++) {
            int n = nw + j*16 + l15;
            float bn = bv[n0 + n];
            #pragma unroll
            for (int i = 0; i < 4; i++) {
                int mloc = mw + i*16 + quad*4;
                union { bf16 h4[4]; uint2 u; } pk;
                #pragma unroll
                for (int r = 0; r < 4; r++) pk.h4[r] = (bf16)(acc[2][i][j][r] + bn);
                *(uint2*)&epi[n*136 + mloc] = pk.u;
            }
        }
        __syncthreads();
        #pragma unroll
        for (int p = 0; p < 4; p++) {
            int c = t + 256*p;
            int row = c >> 4;             // local n (hd)
            int mcol = (c & 15) * 8;      // local m (token)
            int4 val = *(const int4*)&epi[row*136 + mcol];
            int m = m0 + mcol; int bb = m >> 11, s = m & 2047;
            *(int4*)&Vo[((size_t)((bb*H_ + hh)*HD_ + row))*S_ + s] = val;
        }
    }
}

// ---------------- output projection GEMM (64x128 tile) — r7 version ----------
__global__ __launch_bounds__(256) void k_gemm_out(
    const bf16* __restrict__ X, const bf16* __restrict__ W,
    const float* __restrict__ bias, float* __restrict__ Out)
{
    const int n0 = blockIdx.x * 128;
    const int m0 = blockIdx.y * 64;
    const int t = threadIdx.x;
    const int w = t >> 6, lane = t & 63, quad = lane >> 4, l15 = lane & 15;
    const int lr = lane >> 3;
    const int lc = (lane & 7) ^ lr;
    const int sx = l15 & 7;
    const int nw = w * 32;

    __shared__ __align__(16) bf16 As[64*64];
    __shared__ __align__(16) bf16 Bs[128*64];

    f32x4 acc[4][2];
    #pragma unroll
    for (int i = 0; i < 4; i++)
        #pragma unroll
        for (int j = 0; j < 2; j++)
            acc[i][j] = (f32x4){0.f,0.f,0.f,0.f};

    const bf16* gA = X + (size_t)(m0 + w*8 + lr)*D_ + lc*8;
    const bf16* gB = W + (size_t)(n0 + w*8 + lr)*D_ + lc*8;

    for (int k0 = 0; k0 < D_; k0 += 64) {
        #pragma unroll
        for (int c = 0; c < 2; c++)
            gload16(gA + (size_t)c*32*D_ + k0, &As[c*2048 + w*512]);
        #pragma unroll
        for (int c = 0; c < 4; c++)
            gload16(gB + (size_t)c*32*D_ + k0, &Bs[c*2048 + w*512]);
        __syncthreads();
        #pragma unroll
        for (int ks = 0; ks < 2; ks++) {
            bf16x8 af[4], bfr[2];
            #pragma unroll
            for (int i = 0; i < 4; i++)
                af[i] = *(const bf16x8*)&As[(i*16 + l15)*64 + (((ks*4+quad)^sx)*8)];
            #pragma unroll
            for (int j = 0; j < 2; j++)
                bfr[j] = *(const bf16x8*)&Bs[(nw + j*16 + l15)*64 + (((ks*4+quad)^sx)*8)];
            #pragma unroll
            for (int i = 0; i < 4; i++)
                #pragma unroll
                for (int j = 0; j < 2; j++)
                    acc[i][j] = __builtin_amdgcn_mfma_f32_16x16x32_bf16(af[i], bfr[j], acc[i][j], 0, 0, 0);
        }
        __syncthreads();
    }

    #pragma unroll
    for (int j = 0; j < 2; j++) {
        int n = n0 + nw + j*16 + l15;
        float bn = bias[n];
        #pragma unroll
        for (int i = 0; i < 4; i++) {
            int mbase = m0 + i*16 + quad*4;
            #pragma unroll
            for (int r = 0; r < 4; r++)
                Out[(size_t)(mbase + r)*D_ + n] = acc[i][j][r] + bn;
        }
    }
}

// ---------------- fused attention v8r (proven 51.4-51.8 us — unchanged) ------
#define ATT_PAIR(BUFA, K0, PF)                                                  \
  {                                                                             \
    if (PF) {                                                                   \
      const int kp = (K0) + 128;                                                \
      _Pragma("unroll")                                                         \
      for (int c = 0; c < 2; c++) {                                             \
        gload16(KstK + (size_t)(kp + c*32)*HD_,      &Ks[(BUFA)^2][c*2048 + w*512]);     \
        gload16(VstV + (size_t)c*32*S_ + kp,         &Vs[(BUFA)^2][c*2048 + w*512]);     \
        gload16(KstK + (size_t)(kp + 64 + c*32)*HD_, &Ks[((BUFA)^2)+1][c*2048 + w*512]); \
        gload16(VstV + (size_t)c*32*S_ + kp + 64,    &Vs[((BUFA)^2)+1][c*2048 + w*512]); \
      }                                                                         \
    }                                                                           \
    f32x4 st[2][4][2];                                                          \
    _Pragma("unroll")                                                           \
    for (int sub = 0; sub < 2; sub++) {                                         \
      const int kb = (K0) + sub*64;                                             \
      _Pragma("unroll")                                                         \
      for (int g = 0; g < 4; g++) {                                             \
        float4 m4 = *(const float4*)&Ms[kb + quad*8 + (g>>1)*32 + (g&1)*4];     \
        f32x4 sti = (f32x4){m4.x, m4.y, m4.z, m4.w} * 10000.f - 10000.f;        \
        st[sub][g][0] = sti;                                                    \
        st[sub][g][1] = sti;                                                    \
      }                                                                         \
    }                                                                           \
    __builtin_amdgcn_s_setprio(1);                                              \
    _Pragma("unroll")                                                           \
    for (int sub = 0; sub < 2; sub++) {                                         \
      _Pragma("unroll")                                                         \
      for (int ks = 0; ks < 2; ks++) {                                          \
        _Pragma("unroll")                                                       \
        for (int g = 0; g < 4; g++) {                                           \
          const int kk = g >> 1, hf = g & 1;                                    \
          bf16x8 af = *(const bf16x8*)&Ks[(BUFA)+sub][(arow + hf*4 + kk*32)*64 + (((ks*4+quad)^sx)*8)]; \
          _Pragma("unroll")                                                     \
          for (int m2 = 0; m2 < 2; m2++)                                        \
            st[sub][g][m2] = __builtin_amdgcn_mfma_f32_16x16x32_bf16(af, qf[m2][ks], st[sub][g][m2], 0, 0, 0); \
        }                                                                       \
      }                                                                         \
    }                                                                           \
    __builtin_amdgcn_s_setprio(0);                                              \
    _Pragma("unroll")                                                           \
    for (int sub = 0; sub < 2; sub++) {                                         \
      bf16x8 pa[2][2];                                                          \
      _Pragma("unroll")                                                         \
      for (int m2 = 0; m2 < 2; m2++) {                                          \
        _Pragma("unroll")                                                       \
        for (int kk = 0; kk < 2; kk++) {                                        \
          union { bf16 h8[8]; bf16x8 v; } pk;                                   \
          _Pragma("unroll")                                                     \
          for (int hf = 0; hf < 2; hf++) {                                      \
            f32x4 sv = st[sub][kk*2 + hf][m2];                                  \
            f32x2 lo, hi;                                                       \
            lo.x = __builtin_amdgcn_fmed3f(sv[0], -3.f, 3.f);                   \
            lo.y = __builtin_amdgcn_fmed3f(sv[1], -3.f, 3.f);                   \
            hi.x = __builtin_amdgcn_fmed3f(sv[2], -3.f, 3.f);                   \
            hi.y = __builtin_amdgcn_fmed3f(sv[3], -3.f, 3.f);                   \
            f32x2 tlo = lo * lo * (-0.01f) + 0.25f;                             \
            f32x2 thi = hi * hi * (-0.01f) + 0.25f;                             \
            f32x2 slo = lo * tlo + 0.5f;                                        \
            f32x2 shi = hi * thi + 0.5f;                                        \
            lacv[m2] += slo;                                                    \
            lacv[m2] += shi;                                                    \
            pk.h8[hf*4+0] = (bf16)slo.x; pk.h8[hf*4+1] = (bf16)slo.y;           \
            pk.h8[hf*4+2] = (bf16)shi.x; pk.h8[hf*4+3] = (bf16)shi.y;           \
          }                                                                     \
          pa[m2][kk] = pk.v;                                                    \
        }                                                                       \
      }                                                                         \
      _Pragma("unroll")                                                         \
      for (int kk = 0; kk < 2; kk++) {                                          \
        bf16x8 vf[4];                                                           \
        _Pragma("unroll")                                                       \
        for (int nt = 0; nt < 4; nt++)                                          \
          vf[nt] = *(const bf16x8*)&Vs[(BUFA)+sub][(nt*16 + l15)*64 + (((kk*4+quad)^sx)*8)]; \
        __builtin_amdgcn_s_setprio(1);                                          \
        _Pragma("unroll")                                                       \
        for (int m2 = 0; m2 < 2; m2++)                                          \
          _Pragma("unroll")                                                     \
          for (int nt = 0; nt < 4; nt++)                                        \
            cacc[m2][nt] = __builtin_amdgcn_mfma_f32_16x16x32_bf16(pa[m2][kk], vf[nt], cacc[m2][nt], 0, 0, 0); \
        __builtin_amdgcn_s_setprio(0);                                          \
      }                                                                         \
    }                                                                           \
    asm volatile("s_waitcnt vmcnt(0)\n\ts_barrier" ::: "memory");               \
  }

__global__ __launch_bounds__(256, 2) void k_attn(
    const bf16* __restrict__ Q, const bf16* __restrict__ K, const bf16* __restrict__ Vt,
    const float* __restrict__ mask, bf16* __restrict__ Ctx)
{
    const int bh = blockIdx.y;
    const int b = bh >> 4, h = bh & 15;
    const int q0 = blockIdx.x * 128;
    const int t = threadIdx.x;
    const int w = t >> 6, lane = t & 63, quad = lane >> 4, l15 = lane & 15;
    const int lr = lane >> 3;
    const int lcV = (lane & 7) ^ lr;                          // Vs swizzle: row&7
    const int lcK = (lane & 7) ^ ((lr & 3) | ((w & 1) << 2)); // Ks swizzle: row bits {0,1,3}
    const int sx = l15 & 7;
    const int arow = ((l15 & 12) << 1) | (l15 & 3);           // bit-spread A-row base

    __shared__ __align__(16) bf16 Ks[4][64*64];   // 32 KB
    __shared__ __align__(16) bf16 Vs[4][64*64];   // 32 KB
    __shared__ __align__(16) float Ms[S_];        //  8 KB mask row for batch b

    // Q B-frags for this wave's 32 q-rows (4 frags, 16 VGPRs)
    bf16x8 qf[2][2];
    const bf16* Qbase = Q + ((size_t)bh*S_ + q0 + w*32)*HD_;
    #pragma unroll
    for (int m2 = 0; m2 < 2; m2++)
        #pragma unroll
        for (int ks = 0; ks < 2; ks++)
            qf[m2][ks] = *(const bf16x8*)&Qbase[(size_t)(m2*16 + l15)*HD_ + ks*32 + quad*8];

    f32x4 cacc[2][4];
    #pragma unroll
    for (int i = 0; i < 2; i++)
        #pragma unroll
        for (int j = 0; j < 4; j++)
            cacc[i][j] = (f32x4){0.f,0.f,0.f,0.f};
    f32x2 lacv[2];
    #pragma unroll
    for (int m2 = 0; m2 < 2; m2++) lacv[m2] = (f32x2){0.f,0.f};

    const bf16* KstK = K  + ((size_t)bh*S_  + w*8 + lr)*HD_ + lcK*8;
    const bf16* VstV = Vt + ((size_t)bh*HD_ + w*8 + lr)*S_  + lcV*8;

    // ---- prologue: mask row -> LDS; stage tiles 0,1 into bufs 0,1 ----
    {
        const float* mg = mask + (size_t)b*S_ + t*8;
        float4 a0 = *(const float4*)mg;
        float4 a1 = *(const float4*)(mg + 4);
        *(float4*)&Ms[t*8]     = a0;
        *(float4*)&Ms[t*8 + 4] = a1;
    }
    #pragma unroll
    for (int c = 0; c < 2; c++) {
        gload16(KstK + (size_t)(c*32)*HD_,      &Ks[0][c*2048 + w*512]);
        gload16(VstV + (size_t)c*32*S_,         &Vs[0][c*2048 + w*512]);
        gload16(KstK + (size_t)(64 + c*32)*HD_, &Ks[1][c*2048 + w*512]);
        gload16(VstV + (size_t)c*32*S_ + 64,    &Vs[1][c*2048 + w*512]);
    }
    asm volatile("s_waitcnt vmcnt(0) lgkmcnt(0)\n\ts_barrier" ::: "memory");

    // main loop: 16 pairs, alternating buffer sets {0,1} / {2,3}
    for (int q2 = 0; q2 < S_/256; q2++) {       // 8 outer iterations
        const int k0 = q2 * 256;
        ATT_PAIR(0, k0,        true);
        ATT_PAIR(2, k0 + 128,  (q2 < S_/256 - 1));
    }

    // epilogue: row-sums fully within the wave (quads hold disjoint k subsets)
    float s[2];
    #pragma unroll
    for (int m2 = 0; m2 < 2; m2++) {
        float v = lacv[m2].x + lacv[m2].y;
        v += __shfl_xor(v, 16);
        v += __shfl_xor(v, 32);
        s[m2] = v;   // lane l now holds rowsum for q = m2*16 + (l&15)
    }

    #pragma unroll
    for (int m2 = 0; m2 < 2; m2++) {
        #pragma unroll
        for (int r = 0; r < 4; r++) {
            float rs = __shfl(s[m2], quad*4 + r);   // redistribute l15-indexed -> row-indexed
            float rinv = 1.0f / (rs + 1e-8f);
            size_t row = (size_t)(b*S_ + q0 + w*32 + m2*16 + quad*4 + r);
            #pragma unroll
            for (int nt = 0; nt < 4; nt++)
                Ctx[row*D_ + h*HD_ + nt*16 + l15] = (bf16)(cacc[m2][nt][r] * rinv);
        }
    }
}

extern "C" void kernel_launch(void* const* d_in, const int* in_sizes, int n_in,
                              void* d_out, int out_size, void* d_ws, size_t ws_size,
                              hipStream_t stream) {
    const float* hs   = (const float*)d_in[0];
    const float* mask = (const float*)d_in[1];
    const float* Wq   = (const float*)d_in[2];
    const float* bq   = (const float*)d_in[3];
    const float* Wk   = (const float*)d_in[4];
    const float* bk   = (const float*)d_in[5];
    const float* Wv   = (const float*)d_in[6];
    const float* bv   = (const float*)d_in[7];
    const float* Wo   = (const float*)d_in[8];
    const float* bo   = (const float*)d_in[9];
    float* out = (float*)d_out;

    char* ws = (char*)d_ws;
    const size_t MB = 1024*1024;
    bf16* hb   = (bf16*)(ws);            // [M_,D_]        8 MB
    bf16* wqb  = (bf16*)(ws + 8*MB);     // [D_,D_]        2 MB
    bf16* wkb  = (bf16*)(ws + 10*MB);
    bf16* wvb  = (bf16*)(ws + 12*MB);
    bf16* wob  = (bf16*)(ws + 14*MB);
    bf16* qb   = (bf16*)(ws + 16*MB);    // [BH][S][HD]    8 MB
    bf16* kb   = (bf16*)(ws + 24*MB);    // [BH][S][HD]    8 MB
    bf16* vtb  = (bf16*)(ws + 32*MB);    // [BH][HD][S]    8 MB
    bf16* ctxb = (bf16*)(ws + 40*MB);    // [M_,D_]        8 MB

    k_cvt_all<<<2048 + 4*512, 256, 0, stream>>>(hs, Wq, Wk, Wv, Wo, hb, wqb, wkb, wvb, wob);

    k_gemm_qkv<<<dim3(H_, M_/128), 256, 0, stream>>>(
        hb, wqb, wkb, wvb, bq, bk, bv, qb, kb, vtb);

    k_attn<<<dim3(S_/128, B_*H_), 256, 0, stream>>>(qb, kb, vtb, mask, ctxb);

    k_gemm_out<<<dim3(D_/128, M_/64), 256, 0, stream>>>(ctxb, wob, bo, out);
}